// Round 3
// baseline (9309.682 us; speedup 1.0000x reference)
//
#include <hip/hip_runtime.h>
#include <math.h>

#define BATCH   131072
#define IN_F    80
#define EMB     64
#define NE      16
#define RANK    8
#define UDIM    16
#define NCLS    10
#define NUSERS  1000
#define W2P     12
#define HPAD    66    // h1 LDS row stride: 2-way bank alias (free), not 16B-aligned so b32 I/O

// ---- workspace layout (bytes) ----
#define OFF_H      0ull                 // BATCH*64 f32      = 33554432
#define OFF_A      33554432ull          // NUSERS*16*64 f32  =  4096000
#define OFF_TOPE   37650432ull          // 2*BATCH int
#define OFF_TOPW   38699008ull          // 2*BATCH f32
#define OFF_PAIRB  39747584ull          // 2*BATCH int
#define OFF_PAIRW  40796160ull          // 2*BATCH f32
#define OFF_HIST   41844736ull
#define OFF_OFFS   41845760ull
#define OFF_CUR    41846784ull

__device__ __forceinline__ float gelu_f(float v) {
    return 0.5f * v * (1.0f + erff(v * 0.70710678118654752440f));
}

// ---------------- A[u][e][d] = sum_r gU[e][d][r] * (sum_dd ut[u][dd]*gV[e][dd][r]) ----------------
__global__ void k_prep(const float* __restrict__ gU, const float* __restrict__ gV,
                       const float* __restrict__ ut, float* __restrict__ A)
{
    int idx = blockIdx.x * 256 + threadIdx.x;
    if (idx >= NUSERS * NE) return;
    int u = idx / NE, e = idx - u * NE;

    float uvec[UDIM];
    const float4* up = (const float4*)(ut + (size_t)u * UDIM);
#pragma unroll
    for (int t = 0; t < UDIM / 4; ++t) {
        float4 v = up[t];
        uvec[4*t+0] = v.x; uvec[4*t+1] = v.y; uvec[4*t+2] = v.z; uvec[4*t+3] = v.w;
    }

    float uv[RANK];
#pragma unroll
    for (int r = 0; r < RANK; ++r) uv[r] = 0.0f;
    const float4* gv4 = (const float4*)gV;
#pragma unroll
    for (int dd = 0; dd < UDIM; ++dd) {
        float4 g0 = gv4[(e * UDIM + dd) * 2 + 0];
        float4 g1 = gv4[(e * UDIM + dd) * 2 + 1];
        float ud = uvec[dd];
        uv[0] = fmaf(ud, g0.x, uv[0]); uv[1] = fmaf(ud, g0.y, uv[1]);
        uv[2] = fmaf(ud, g0.z, uv[2]); uv[3] = fmaf(ud, g0.w, uv[3]);
        uv[4] = fmaf(ud, g1.x, uv[4]); uv[5] = fmaf(ud, g1.y, uv[5]);
        uv[6] = fmaf(ud, g1.z, uv[6]); uv[7] = fmaf(ud, g1.w, uv[7]);
    }

    const float4* gu4 = (const float4*)gU;
    float4* Ao = (float4*)(A + ((size_t)u * NE + e) * EMB);
#pragma unroll
    for (int d4 = 0; d4 < EMB / 4; ++d4) {
        float4 o;
        float* op = (float*)&o;
#pragma unroll
        for (int j = 0; j < 4; ++j) {
            int d = 4 * d4 + j;
            float4 q0 = gu4[(e * EMB + d) * 2 + 0];
            float4 q1 = gu4[(e * EMB + d) * 2 + 1];
            float a = 0.0f;
            a = fmaf(q0.x, uv[0], a); a = fmaf(q0.y, uv[1], a);
            a = fmaf(q0.z, uv[2], a); a = fmaf(q0.w, uv[3], a);
            a = fmaf(q1.x, uv[4], a); a = fmaf(q1.y, uv[5], a);
            a = fmaf(q1.z, uv[6], a); a = fmaf(q1.w, uv[7], a);
            op[j] = a;
        }
        Ao[d4] = o;
    }
}

// ---------------- fused backbone + gate, 128 threads, streaming/low-register ----------------
__global__ __launch_bounds__(128) void k_fused(
    const float* __restrict__ x, const int* __restrict__ uid,
    const float* __restrict__ w1, const float* __restrict__ b1,
    const float* __restrict__ w2, const float* __restrict__ b2,
    const float* __restrict__ gam, const float* __restrict__ bet,
    const float* __restrict__ A, const float* __restrict__ gb,
    float* __restrict__ h_out,
    int* __restrict__ top_e, float* __restrict__ top_w, int* __restrict__ hist)
{
    // union: w1 (80*64 = 5120 floats) then per-thread h1 rows (128*66 = 8448 floats)
    __shared__ __align__(16) float s_buf[128 * HPAD];   // 33792 B
    __shared__ __align__(16) float s_w2[EMB * EMB];     // 16384 B
    __shared__ __align__(16) float s_b1[EMB];
    __shared__ __align__(16) float s_b2[EMB];
    __shared__ __align__(16) float s_gam[EMB];
    __shared__ __align__(16) float s_bet[EMB];
    __shared__ int s_hist[NE];

    const int tid = threadIdx.x;
    for (int i = tid; i < IN_F * EMB; i += 128) s_buf[i] = w1[i];
    for (int i = tid; i < EMB * EMB; i += 128) s_w2[i] = w2[i];
    if (tid < EMB) { s_b1[tid] = b1[tid]; s_b2[tid] = b2[tid]; s_gam[tid] = gam[tid]; s_bet[tid] = bet[tid]; }
    if (tid < NE) s_hist[tid] = 0;
    __syncthreads();

    const int b = blockIdx.x * 128 + tid;

    // ---- fc1: h1[k] = gelu(b1[k] + sum_d x[d]*w1[d][k]), d-outer, x streamed ----
    float h1[EMB];
    {
        const float4* sb = (const float4*)s_b1;
#pragma unroll
        for (int k4 = 0; k4 < 16; ++k4) {
            float4 v = sb[k4];
            h1[4*k4+0] = v.x; h1[4*k4+1] = v.y; h1[4*k4+2] = v.z; h1[4*k4+3] = v.w;
        }
        const float4* xp = (const float4*)(x + (size_t)b * IN_F);
        const float4* sw = (const float4*)s_buf;
#pragma unroll
        for (int t = 0; t < IN_F / 4; ++t) {
            float4 xv = xp[t];
            float xs[4] = {xv.x, xv.y, xv.z, xv.w};
#pragma unroll
            for (int j = 0; j < 4; ++j) {
                const int d = 4 * t + j;
                const float xd = xs[j];
#pragma unroll
                for (int k4 = 0; k4 < 16; ++k4) {
                    float4 w = sw[d * 16 + k4];            // uniform addr: broadcast
                    h1[4*k4+0] = fmaf(xd, w.x, h1[4*k4+0]);
                    h1[4*k4+1] = fmaf(xd, w.y, h1[4*k4+1]);
                    h1[4*k4+2] = fmaf(xd, w.z, h1[4*k4+2]);
                    h1[4*k4+3] = fmaf(xd, w.w, h1[4*k4+3]);
                }
            }
        }
#pragma unroll
        for (int k = 0; k < EMB; ++k) h1[k] = gelu_f(h1[k]);
    }

    __syncthreads();                       // all w1 reads done before overwrite
#pragma unroll
    for (int k = 0; k < EMB; ++k) s_buf[tid * HPAD + k] = h1[k];   // controlled LDS "spill"
    // (each thread reads back only its own row -> no sync needed)

    // ---- fc2: hv[k] = gelu(b2[k] + sum_d h1[d]*w2[d][k]), d-outer, h1 from LDS ----
    float hv[EMB];
    {
        const float4* sb = (const float4*)s_b2;
#pragma unroll
        for (int k4 = 0; k4 < 16; ++k4) {
            float4 v = sb[k4];
            hv[4*k4+0] = v.x; hv[4*k4+1] = v.y; hv[4*k4+2] = v.z; hv[4*k4+3] = v.w;
        }
        const float4* sw = (const float4*)s_w2;
#pragma unroll
        for (int d = 0; d < EMB; ++d) {
            float hd = s_buf[tid * HPAD + d];
#pragma unroll
            for (int k4 = 0; k4 < 16; ++k4) {
                float4 w = sw[d * 16 + k4];                // broadcast
                hv[4*k4+0] = fmaf(hd, w.x, hv[4*k4+0]);
                hv[4*k4+1] = fmaf(hd, w.y, hv[4*k4+1]);
                hv[4*k4+2] = fmaf(hd, w.z, hv[4*k4+2]);
                hv[4*k4+3] = fmaf(hd, w.w, hv[4*k4+3]);
            }
        }
#pragma unroll
        for (int k = 0; k < EMB; ++k) hv[k] = gelu_f(hv[k]);
    }

    // ---- LayerNorm (identical numerics to prior rounds) ----
    float mu = 0.0f;
#pragma unroll
    for (int k = 0; k < EMB; ++k) mu += hv[k];
    mu *= (1.0f / EMB);
    float var = 0.0f;
#pragma unroll
    for (int k = 0; k < EMB; ++k) { float t = hv[k] - mu; var = fmaf(t, t, var); }
    var *= (1.0f / EMB);
    float inv = 1.0f / sqrtf(var + 1e-5f);
#pragma unroll
    for (int k = 0; k < EMB; ++k) hv[k] = (hv[k] - mu) * inv * s_gam[k] + s_bet[k];

    {
        float4* ho = (float4*)(h_out + (size_t)b * EMB);
#pragma unroll
        for (int k4 = 0; k4 < 16; ++k4) {
            float4 o;
            o.x = hv[4*k4+0]; o.y = hv[4*k4+1]; o.z = hv[4*k4+2]; o.w = hv[4*k4+3];
            ho[k4] = o;
        }
    }

    // ---- gate (identical to round-2 pass) ----
    const int u = uid[b];
    const float* Arow = A + (size_t)u * NE * EMB;
    float g[NE];
#pragma unroll
    for (int e = 0; e < NE; ++e) {
        const float4* ap = (const float4*)(Arow + e * EMB);
        float4 acc = make_float4(0.f, 0.f, 0.f, 0.f);
#pragma unroll
        for (int t = 0; t < EMB / 4; ++t) {
            float4 a4 = ap[t];
            acc.x = fmaf(hv[4*t+0], a4.x, acc.x);
            acc.y = fmaf(hv[4*t+1], a4.y, acc.y);
            acc.z = fmaf(hv[4*t+2], a4.z, acc.z);
            acc.w = fmaf(hv[4*t+3], a4.w, acc.w);
        }
        g[e] = (acc.x + acc.y) + (acc.z + acc.w) + gb[e];
    }

    float m = g[0];
#pragma unroll
    for (int e = 1; e < NE; ++e) m = fmaxf(m, g[e]);
    float w[NE];
    float s = 0.0f;
#pragma unroll
    for (int e = 0; e < NE; ++e) { w[e] = expf(g[e] - m); s += w[e]; }
    float sinv = 1.0f / s;
#pragma unroll
    for (int e = 0; e < NE; ++e) w[e] *= sinv;

    int i0 = 0; float b0 = w[0];
#pragma unroll
    for (int e = 1; e < NE; ++e) { if (w[e] > b0) { b0 = w[e]; i0 = e; } }
    int i1 = (i0 == 0) ? 1 : 0; float b1v = w[i1];
#pragma unroll
    for (int e = 0; e < NE; ++e) {
        if (e != i0 && w[e] > b1v) { b1v = w[e]; i1 = e; }
    }
    float denom = fmaxf(b0 + b1v, 1e-9f);
    float w0n = b0 / denom, w1n = b1v / denom;

    top_e[2*b+0] = i0; top_w[2*b+0] = w0n;
    top_e[2*b+1] = i1; top_w[2*b+1] = w1n;
    atomicAdd(&s_hist[i0], 1);
    atomicAdd(&s_hist[i1], 1);
    __syncthreads();
    if (tid < NE) atomicAdd(&hist[tid], s_hist[tid]);
}

// ---------------- tiny exclusive scan over 16 bins ----------------
__global__ void k_scan(const int* __restrict__ hist, int* __restrict__ offs, int* __restrict__ cur)
{
    if (blockIdx.x == 0 && threadIdx.x == 0) {
        int acc = 0;
        for (int e = 0; e < NE; ++e) { offs[e] = acc; cur[e] = acc; acc += hist[e]; }
    }
}

// ---------------- block-aggregated scatter ----------------
__global__ __launch_bounds__(256) void k_scatter(
    const int* __restrict__ top_e, const float* __restrict__ top_w,
    int* __restrict__ cur, int* __restrict__ pair_b, float* __restrict__ pair_w)
{
    __shared__ int lh[NE];
    __shared__ int lbase[NE];
    const int tid = threadIdx.x;
    if (tid < NE) lh[tid] = 0;
    __syncthreads();

    const int b = blockIdx.x * 256 + tid;
    const int e0 = top_e[2*b+0];
    const int e1 = top_e[2*b+1];
    atomicAdd(&lh[e0], 1);
    atomicAdd(&lh[e1], 1);
    __syncthreads();
    if (tid < NE) {
        lbase[tid] = atomicAdd(&cur[tid], lh[tid]);
        lh[tid] = 0;
    }
    __syncthreads();
    int r0 = atomicAdd(&lh[e0], 1);
    int p0 = lbase[e0] + r0;
    pair_b[p0] = b; pair_w[p0] = top_w[2*b+0];
    int r1 = atomicAdd(&lh[e1], 1);
    int p1 = lbase[e1] + r1;
    pair_b[p1] = b; pair_w[p1] = top_w[2*b+1];
}

// ---------------- expert: z[64]-in-reg, d-outer, h streamed, weights broadcast ----------------
#define EXP_BX 512
__global__ __launch_bounds__(128) void k_expert(
    const float* __restrict__ h,
    const int* __restrict__ pair_b, const float* __restrict__ pair_w,
    const int* __restrict__ hist, const int* __restrict__ offs,
    const float* __restrict__ ew1, const float* __restrict__ eb1,
    const float* __restrict__ eg, const float* __restrict__ ebeta,
    const float* __restrict__ ew2, const float* __restrict__ eb2,
    float* __restrict__ out)
{
    const int e = blockIdx.y;
    const int cnt = hist[e];
    if ((int)(blockIdx.x * 128) >= cnt) return;

    __shared__ __align__(16) float s_w1[EMB * EMB];    // 16 KB
    __shared__ __align__(16) float s_w2p[EMB * W2P];   // 3 KB
    __shared__ __align__(16) float s_b1[EMB];
    __shared__ __align__(16) float s_g[EMB];
    __shared__ __align__(16) float s_be[EMB];
    __shared__ __align__(16) float s_b2p[W2P];

    const int tid = threadIdx.x;
    for (int i = tid; i < EMB * EMB; i += 128) s_w1[i] = ew1[(size_t)e * EMB * EMB + i];
    for (int i = tid; i < EMB * W2P; i += 128) {
        int k = i / W2P, c = i - k * W2P;
        s_w2p[i] = (c < NCLS) ? ew2[((size_t)e * EMB + k) * NCLS + c] : 0.0f;
    }
    if (tid < EMB) { s_b1[tid] = eb1[e * EMB + tid]; s_g[tid] = eg[e * EMB + tid]; s_be[tid] = ebeta[e * EMB + tid]; }
    if (tid < W2P) s_b2p[tid] = (tid < NCLS) ? eb2[e * NCLS + tid] : 0.0f;
    __syncthreads();

    const int base = offs[e];
    for (int l0 = blockIdx.x * 128; l0 < cnt; l0 += EXP_BX * 128) {
        const int lane = l0 + tid;
        if (lane >= cnt) continue;
        const int idx = base + lane;
        const int b = pair_b[idx];
        const float pw = pair_w[idx];

        // fc1: z[k] = b1[k] + sum_d h[b][d]*w1[d][k], d-outer, h streamed float4
        float z[EMB];
        {
            const float4* sb = (const float4*)s_b1;
#pragma unroll
            for (int k4 = 0; k4 < 16; ++k4) {
                float4 v = sb[k4];
                z[4*k4+0] = v.x; z[4*k4+1] = v.y; z[4*k4+2] = v.z; z[4*k4+3] = v.w;
            }
            const float4* hp = (const float4*)(h + (size_t)b * EMB);
            const float4* sw = (const float4*)s_w1;
#pragma unroll
            for (int t = 0; t < 16; ++t) {
                float4 hv4 = hp[t];
                float hs[4] = {hv4.x, hv4.y, hv4.z, hv4.w};
#pragma unroll
                for (int j = 0; j < 4; ++j) {
                    const int d = 4 * t + j;
                    const float hd = hs[j];
#pragma unroll
                    for (int k4 = 0; k4 < 16; ++k4) {
                        float4 w = sw[d * 16 + k4];        // broadcast
                        z[4*k4+0] = fmaf(hd, w.x, z[4*k4+0]);
                        z[4*k4+1] = fmaf(hd, w.y, z[4*k4+1]);
                        z[4*k4+2] = fmaf(hd, w.z, z[4*k4+2]);
                        z[4*k4+3] = fmaf(hd, w.w, z[4*k4+3]);
                    }
                }
            }
#pragma unroll
            for (int k = 0; k < EMB; ++k) z[k] = gelu_f(z[k]);
        }

        // LayerNorm
        float mu = 0.0f;
#pragma unroll
        for (int k = 0; k < EMB; ++k) mu += z[k];
        mu *= (1.0f / EMB);
        float var = 0.0f;
#pragma unroll
        for (int k = 0; k < EMB; ++k) { float t = z[k] - mu; var = fmaf(t, t, var); }
        var *= (1.0f / EMB);
        float inv = 1.0f / sqrtf(var + 1e-5f);
#pragma unroll
        for (int k = 0; k < EMB; ++k) z[k] = (z[k] - mu) * inv * s_g[k] + s_be[k];

        // fc2: a[c] = b2[c] + sum_k z[k]*w2[k][c], k-outer
        float a[W2P];
        {
            const float4* sb2 = (const float4*)s_b2p;
            float4 a0 = sb2[0], a1 = sb2[1], a2 = sb2[2];
            const float4* sw2 = (const float4*)s_w2p;
#pragma unroll
            for (int k = 0; k < EMB; ++k) {
                float zk = z[k];
                float4 q0 = sw2[k * 3 + 0];                // broadcast
                float4 q1 = sw2[k * 3 + 1];
                float4 q2 = sw2[k * 3 + 2];
                a0.x = fmaf(zk, q0.x, a0.x); a0.y = fmaf(zk, q0.y, a0.y);
                a0.z = fmaf(zk, q0.z, a0.z); a0.w = fmaf(zk, q0.w, a0.w);
                a1.x = fmaf(zk, q1.x, a1.x); a1.y = fmaf(zk, q1.y, a1.y);
                a1.z = fmaf(zk, q1.z, a1.z); a1.w = fmaf(zk, q1.w, a1.w);
                a2.x = fmaf(zk, q2.x, a2.x); a2.y = fmaf(zk, q2.y, a2.y);
            }
            a[0]=a0.x; a[1]=a0.y; a[2]=a0.z; a[3]=a0.w;
            a[4]=a1.x; a[5]=a1.y; a[6]=a1.z; a[7]=a1.w;
            a[8]=a2.x; a[9]=a2.y; a[10]=0.f; a[11]=0.f;
        }
#pragma unroll
        for (int c = 0; c < NCLS; ++c)
            atomicAdd(out + (size_t)b * NCLS + c, pw * a[c]);
    }
}

extern "C" void kernel_launch(void* const* d_in, const int* in_sizes, int n_in,
                              void* d_out, int out_size, void* d_ws, size_t ws_size,
                              hipStream_t stream)
{
    (void)in_sizes; (void)n_in; (void)out_size; (void)ws_size;

    const float* x     = (const float*)d_in[0];
    const int*   uid   = (const int*)  d_in[1];
    const float* bb_w1 = (const float*)d_in[2];
    const float* bb_b1 = (const float*)d_in[3];
    const float* bb_w2 = (const float*)d_in[4];
    const float* bb_b2 = (const float*)d_in[5];
    const float* bb_g  = (const float*)d_in[6];
    const float* bb_be = (const float*)d_in[7];
    const float* gU    = (const float*)d_in[8];
    const float* gV    = (const float*)d_in[9];
    const float* gb    = (const float*)d_in[10];
    const float* e_w1  = (const float*)d_in[11];
    const float* e_b1  = (const float*)d_in[12];
    const float* e_g   = (const float*)d_in[13];
    const float* e_be  = (const float*)d_in[14];
    const float* e_w2  = (const float*)d_in[15];
    const float* e_b2  = (const float*)d_in[16];
    const float* ut    = (const float*)d_in[17];

    float* out = (float*)d_out;
    char*  ws  = (char*)d_ws;

    float* h      = (float*)(ws + OFF_H);
    float* A      = (float*)(ws + OFF_A);
    int*   top_e  = (int*)  (ws + OFF_TOPE);
    float* top_w  = (float*)(ws + OFF_TOPW);
    int*   pair_b = (int*)  (ws + OFF_PAIRB);
    float* pair_w = (float*)(ws + OFF_PAIRW);
    int*   hist   = (int*)  (ws + OFF_HIST);
    int*   offs   = (int*)  (ws + OFF_OFFS);
    int*   cur    = (int*)  (ws + OFF_CUR);

    hipMemsetAsync(out, 0, (size_t)BATCH * NCLS * sizeof(float), stream);
    hipMemsetAsync(hist, 0, NE * sizeof(int), stream);

    k_prep<<<(NUSERS * NE + 255) / 256, 256, 0, stream>>>(gU, gV, ut, A);
    k_fused<<<BATCH / 128, 128, 0, stream>>>(x, uid, bb_w1, bb_b1, bb_w2, bb_b2,
                                             bb_g, bb_be, A, gb, h, top_e, top_w, hist);
    k_scan<<<1, 64, 0, stream>>>(hist, offs, cur);
    k_scatter<<<BATCH / 256, 256, 0, stream>>>(top_e, top_w, cur, pair_b, pair_w);
    dim3 eg(EXP_BX, NE);
    k_expert<<<eg, 128, 0, stream>>>(h, pair_b, pair_w, hist, offs,
                                     e_w1, e_b1, e_g, e_be, e_w2, e_b2, out);
}

// Round 4
// 457.487 us; speedup vs baseline: 20.3496x; 20.3496x over previous
//
#include <hip/hip_runtime.h>
#include <math.h>

#define BATCH   131072
#define IN_F    80
#define EMB     64
#define NE      16
#define RANK    8
#define UDIM    16
#define NCLS    10
#define NUSERS  1000
#define HSTRIDE 65     // LDS row stride: bank (i+d)%32, 2 lanes/bank = free

// ---- workspace layout (bytes) ----
#define OFF_H      0ull                 // BATCH*64 f32      = 33554432
#define OFF_A      33554432ull          // NUSERS*16*64 f32  =  4096000
#define OFF_TOPE   37650432ull          // 2*BATCH int
#define OFF_TOPW   38699008ull          // 2*BATCH f32
#define OFF_PAIRB  39747584ull          // 2*BATCH int
#define OFF_PAIRW  40796160ull          // 2*BATCH f32
#define OFF_HIST   41844736ull
#define OFF_OFFS   41845760ull
#define OFF_CUR    41846784ull

__device__ __forceinline__ float gelu_f(float v) {
    return 0.5f * v * (1.0f + erff(v * 0.70710678118654752440f));
}
__device__ __forceinline__ float4 gelu4(float4 v) {
    v.x = gelu_f(v.x); v.y = gelu_f(v.y); v.z = gelu_f(v.z); v.w = gelu_f(v.w);
    return v;
}
__device__ __forceinline__ float4 sfma4(float s, float4 w, float4 a) {
    a.x = fmaf(s, w.x, a.x); a.y = fmaf(s, w.y, a.y);
    a.z = fmaf(s, w.z, a.z); a.w = fmaf(s, w.w, a.w);
    return a;
}
__device__ __forceinline__ float4 ffma4(float4 v, float4 w, float4 a) {
    a.x = fmaf(v.x, w.x, a.x); a.y = fmaf(v.y, w.y, a.y);
    a.z = fmaf(v.z, w.z, a.z); a.w = fmaf(v.w, w.w, a.w);
    return a;
}
__device__ __forceinline__ float4 add4(float4 a, float4 b) {
    a.x += b.x; a.y += b.y; a.z += b.z; a.w += b.w; return a;
}
__device__ __forceinline__ float4 ln4(float4 z, float mu, float inv, float4 g, float4 bb) {
    float4 r;
    r.x = fmaf((z.x - mu) * inv, g.x, bb.x);
    r.y = fmaf((z.y - mu) * inv, g.y, bb.y);
    r.z = fmaf((z.z - mu) * inv, g.z, bb.z);
    r.w = fmaf((z.w - mu) * inv, g.w, bb.w);
    return r;
}

// ---------------- A[u][e][d] = sum_r gU[e][d][r] * (sum_dd ut[u][dd]*gV[e][dd][r]) ----------------
__global__ void k_prep(const float* __restrict__ gU, const float* __restrict__ gV,
                       const float* __restrict__ ut, float* __restrict__ A)
{
    int idx = blockIdx.x * 256 + threadIdx.x;
    if (idx >= NUSERS * NE) return;
    int u = idx / NE, e = idx - u * NE;

    const float4* up = (const float4*)(ut + (size_t)u * UDIM);
    float4 u0 = up[0], u1 = up[1], u2 = up[2], u3 = up[3];

    float4 va = make_float4(0.f, 0.f, 0.f, 0.f);   // uv[0..3]
    float4 vb = make_float4(0.f, 0.f, 0.f, 0.f);   // uv[4..7]
    const float4* gv4 = (const float4*)gV;
#define UVSTEP(UD, DD) do { \
        float4 g0 = gv4[(e * UDIM + (DD)) * 2 + 0]; \
        float4 g1 = gv4[(e * UDIM + (DD)) * 2 + 1]; \
        va = sfma4((UD), g0, va); vb = sfma4((UD), g1, vb); } while (0)
    UVSTEP(u0.x, 0);  UVSTEP(u0.y, 1);  UVSTEP(u0.z, 2);  UVSTEP(u0.w, 3);
    UVSTEP(u1.x, 4);  UVSTEP(u1.y, 5);  UVSTEP(u1.z, 6);  UVSTEP(u1.w, 7);
    UVSTEP(u2.x, 8);  UVSTEP(u2.y, 9);  UVSTEP(u2.z, 10); UVSTEP(u2.w, 11);
    UVSTEP(u3.x, 12); UVSTEP(u3.y, 13); UVSTEP(u3.z, 14); UVSTEP(u3.w, 15);
#undef UVSTEP

    const float4* gu4 = (const float4*)gU;
    float* Ao = A + ((size_t)u * NE + e) * EMB;
    for (int d = 0; d < EMB; ++d) {
        float4 q0 = gu4[(e * EMB + d) * 2 + 0];
        float4 q1 = gu4[(e * EMB + d) * 2 + 1];
        float a = 0.0f;
        a = fmaf(q0.x, va.x, a); a = fmaf(q0.y, va.y, a);
        a = fmaf(q0.z, va.z, a); a = fmaf(q0.w, va.w, a);
        a = fmaf(q1.x, vb.x, a); a = fmaf(q1.y, vb.y, a);
        a = fmaf(q1.z, vb.z, a); a = fmaf(q1.w, vb.w, a);
        Ao[d] = a;
    }
}

// ---------------- backbone: fc1+gelu (LDS rows), fc2+gelu (named regs), LN -> h_out ----------------
__global__ __launch_bounds__(128) void k_backbone(
    const float* __restrict__ x,
    const float* __restrict__ w1, const float* __restrict__ b1,
    const float* __restrict__ w2, const float* __restrict__ b2,
    const float* __restrict__ gam, const float* __restrict__ bet,
    float* __restrict__ h_out)
{
    __shared__ __align__(16) float4 s_w1[IN_F * 16];   // 20 KB [d][j4]
    __shared__ __align__(16) float4 s_w2[EMB * 16];    // 16 KB
    __shared__ __align__(16) float4 s_b1[16], s_b2[16], s_ga[16], s_be[16];
    __shared__ float s_hb[128 * HSTRIDE];              // 33.3 KB

    const int tid = threadIdx.x;
    {
        const float4* g1 = (const float4*)w1;
        for (int i = tid; i < IN_F * 16; i += 128) s_w1[i] = g1[i];
        const float4* g2 = (const float4*)w2;
        for (int i = tid; i < EMB * 16; i += 128) s_w2[i] = g2[i];
        if (tid < 16) {
            s_b1[tid] = ((const float4*)b1)[tid];
            s_b2[tid] = ((const float4*)b2)[tid];
            s_ga[tid] = ((const float4*)gam)[tid];
            s_be[tid] = ((const float4*)bet)[tid];
        }
    }
    __syncthreads();

    const int b = blockIdx.x * 128 + tid;
    const float4* xp = (const float4*)(x + (size_t)b * IN_F);
    const int hbase = tid * HSTRIDE;

    // ---- fc1: output-chunked (4x16), named float4 accumulators, h1 -> own LDS row ----
#pragma unroll 1
    for (int kc = 0; kc < 4; ++kc) {
        float4 a0 = s_b1[kc*4+0], a1 = s_b1[kc*4+1], a2 = s_b1[kc*4+2], a3 = s_b1[kc*4+3];
        const float4* wr = s_w1 + kc * 4;
#pragma unroll 4
        for (int t = 0; t < 20; ++t) {
            float4 xv = xp[t];
            a0 = sfma4(xv.x, wr[0], a0); a1 = sfma4(xv.x, wr[1], a1); a2 = sfma4(xv.x, wr[2], a2); a3 = sfma4(xv.x, wr[3], a3); wr += 16;
            a0 = sfma4(xv.y, wr[0], a0); a1 = sfma4(xv.y, wr[1], a1); a2 = sfma4(xv.y, wr[2], a2); a3 = sfma4(xv.y, wr[3], a3); wr += 16;
            a0 = sfma4(xv.z, wr[0], a0); a1 = sfma4(xv.z, wr[1], a1); a2 = sfma4(xv.z, wr[2], a2); a3 = sfma4(xv.z, wr[3], a3); wr += 16;
            a0 = sfma4(xv.w, wr[0], a0); a1 = sfma4(xv.w, wr[1], a1); a2 = sfma4(xv.w, wr[2], a2); a3 = sfma4(xv.w, wr[3], a3); wr += 16;
        }
        float* hw = &s_hb[hbase + kc * 16];
        hw[0]  = gelu_f(a0.x); hw[1]  = gelu_f(a0.y); hw[2]  = gelu_f(a0.z); hw[3]  = gelu_f(a0.w);
        hw[4]  = gelu_f(a1.x); hw[5]  = gelu_f(a1.y); hw[6]  = gelu_f(a1.z); hw[7]  = gelu_f(a1.w);
        hw[8]  = gelu_f(a2.x); hw[9]  = gelu_f(a2.y); hw[10] = gelu_f(a2.z); hw[11] = gelu_f(a2.w);
        hw[12] = gelu_f(a3.x); hw[13] = gelu_f(a3.y); hw[14] = gelu_f(a3.z); hw[15] = gelu_f(a3.w);
    }
    // own-row readback only -> no barrier needed

    // ---- fc2: 4 static chunks -> named z0..zf ----
    float4 z0, z1, z2, z3, z4, z5, z6, z7, z8, z9, za, zb, zc, zd, ze, zf;
#define BB_FC2C(KC, Z0, Z1, Z2, Z3) do { \
    float4 a0 = s_b2[(KC)*4+0], a1 = s_b2[(KC)*4+1], a2 = s_b2[(KC)*4+2], a3 = s_b2[(KC)*4+3]; \
    const float4* wr = s_w2 + (KC) * 4; \
    _Pragma("unroll 2") \
    for (int t = 0; t < 16; ++t) { \
        const float* hr = &s_hb[hbase + 4 * t]; \
        float q0 = hr[0], q1 = hr[1], q2 = hr[2], q3 = hr[3]; \
        a0 = sfma4(q0, wr[0], a0); a1 = sfma4(q0, wr[1], a1); a2 = sfma4(q0, wr[2], a2); a3 = sfma4(q0, wr[3], a3); wr += 16; \
        a0 = sfma4(q1, wr[0], a0); a1 = sfma4(q1, wr[1], a1); a2 = sfma4(q1, wr[2], a2); a3 = sfma4(q1, wr[3], a3); wr += 16; \
        a0 = sfma4(q2, wr[0], a0); a1 = sfma4(q2, wr[1], a1); a2 = sfma4(q2, wr[2], a2); a3 = sfma4(q2, wr[3], a3); wr += 16; \
        a0 = sfma4(q3, wr[0], a0); a1 = sfma4(q3, wr[1], a1); a2 = sfma4(q3, wr[2], a2); a3 = sfma4(q3, wr[3], a3); wr += 16; \
    } \
    Z0 = gelu4(a0); Z1 = gelu4(a1); Z2 = gelu4(a2); Z3 = gelu4(a3); \
} while (0)
    BB_FC2C(0, z0, z1, z2, z3);
    BB_FC2C(1, z4, z5, z6, z7);
    BB_FC2C(2, z8, z9, za, zb);
    BB_FC2C(3, zc, zd, ze, zf);
#undef BB_FC2C

    // ---- LayerNorm over named regs (all static) ----
    float4 sA = add4(add4(add4(z0, z1), add4(z2, z3)), add4(add4(z4, z5), add4(z6, z7)));
    float4 sB = add4(add4(add4(z8, z9), add4(za, zb)), add4(add4(zc, zd), add4(ze, zf)));
    float4 sS = add4(sA, sB);
    float mu = (sS.x + sS.y + sS.z + sS.w) * (1.0f / 64.0f);
    float4 vv = make_float4(0.f, 0.f, 0.f, 0.f);
#define BB_VACC(Z) do { float4 d4; d4.x = (Z).x - mu; d4.y = (Z).y - mu; d4.z = (Z).z - mu; d4.w = (Z).w - mu; \
                        vv = ffma4(d4, d4, vv); } while (0)
    BB_VACC(z0); BB_VACC(z1); BB_VACC(z2); BB_VACC(z3);
    BB_VACC(z4); BB_VACC(z5); BB_VACC(z6); BB_VACC(z7);
    BB_VACC(z8); BB_VACC(z9); BB_VACC(za); BB_VACC(zb);
    BB_VACC(zc); BB_VACC(zd); BB_VACC(ze); BB_VACC(zf);
#undef BB_VACC
    float var = (vv.x + vv.y + vv.z + vv.w) * (1.0f / 64.0f);
    float inv = 1.0f / sqrtf(var + 1e-5f);

    float4* ho = (float4*)(h_out + (size_t)b * EMB);
    ho[0]  = ln4(z0, mu, inv, s_ga[0],  s_be[0]);
    ho[1]  = ln4(z1, mu, inv, s_ga[1],  s_be[1]);
    ho[2]  = ln4(z2, mu, inv, s_ga[2],  s_be[2]);
    ho[3]  = ln4(z3, mu, inv, s_ga[3],  s_be[3]);
    ho[4]  = ln4(z4, mu, inv, s_ga[4],  s_be[4]);
    ho[5]  = ln4(z5, mu, inv, s_ga[5],  s_be[5]);
    ho[6]  = ln4(z6, mu, inv, s_ga[6],  s_be[6]);
    ho[7]  = ln4(z7, mu, inv, s_ga[7],  s_be[7]);
    ho[8]  = ln4(z8, mu, inv, s_ga[8],  s_be[8]);
    ho[9]  = ln4(z9, mu, inv, s_ga[9],  s_be[9]);
    ho[10] = ln4(za, mu, inv, s_ga[10], s_be[10]);
    ho[11] = ln4(zb, mu, inv, s_ga[11], s_be[11]);
    ho[12] = ln4(zc, mu, inv, s_ga[12], s_be[12]);
    ho[13] = ln4(zd, mu, inv, s_ga[13], s_be[13]);
    ho[14] = ln4(ze, mu, inv, s_ga[14], s_be[14]);
    ho[15] = ln4(zf, mu, inv, s_ga[15], s_be[15]);
}

// ---------------- gate: hv in named regs, A gathered from L2/L3, top-2 on g ----------------
__global__ __launch_bounds__(256) void k_gate2(
    const float* __restrict__ h, const int* __restrict__ uid,
    const float* __restrict__ A, const float* __restrict__ gb,
    int* __restrict__ top_e, float* __restrict__ top_w, int* __restrict__ hist)
{
    __shared__ float s_gb[NE];
    __shared__ int s_hist[NE];
    const int tid = threadIdx.x;
    if (tid < NE) { s_gb[tid] = gb[tid]; s_hist[tid] = 0; }
    __syncthreads();

    const int b = blockIdx.x * 256 + tid;
    const float4* hp = (const float4*)(h + (size_t)b * EMB);
    float4 v0 = hp[0],  v1 = hp[1],  v2 = hp[2],  v3 = hp[3];
    float4 v4 = hp[4],  v5 = hp[5],  v6 = hp[6],  v7 = hp[7];
    float4 v8 = hp[8],  v9 = hp[9],  va = hp[10], vb = hp[11];
    float4 vc = hp[12], vd = hp[13], ve = hp[14], vf = hp[15];

    const int u = uid[b];
    const float4* Ap = (const float4*)(A + (size_t)u * NE * EMB);

    float m0 = -1e30f, m1 = -1e30f;
    int i0 = 0, i1 = 0;
#pragma unroll 1
    for (int e = 0; e < NE; ++e) {
        const float4* ap = Ap + e * 16;
        float4 ac = make_float4(0.f, 0.f, 0.f, 0.f);
        ac = ffma4(v0, ap[0],  ac); ac = ffma4(v1, ap[1],  ac);
        ac = ffma4(v2, ap[2],  ac); ac = ffma4(v3, ap[3],  ac);
        ac = ffma4(v4, ap[4],  ac); ac = ffma4(v5, ap[5],  ac);
        ac = ffma4(v6, ap[6],  ac); ac = ffma4(v7, ap[7],  ac);
        ac = ffma4(v8, ap[8],  ac); ac = ffma4(v9, ap[9],  ac);
        ac = ffma4(va, ap[10], ac); ac = ffma4(vb, ap[11], ac);
        ac = ffma4(vc, ap[12], ac); ac = ffma4(vd, ap[13], ac);
        ac = ffma4(ve, ap[14], ac); ac = ffma4(vf, ap[15], ac);
        float ge = ((ac.x + ac.y) + (ac.z + ac.w)) + s_gb[e];
        if (ge > m0)      { m1 = m0; i1 = i0; m0 = ge; i0 = e; }
        else if (ge > m1) { m1 = ge; i1 = e; }
    }

    // top-2 renormalized softmax weights: full denominator cancels
    float t = expf(m1 - m0);
    float w0n = 1.0f / (1.0f + t);
    float w1n = t / (1.0f + t);

    top_e[2*b+0] = i0; top_w[2*b+0] = w0n;
    top_e[2*b+1] = i1; top_w[2*b+1] = w1n;
    atomicAdd(&s_hist[i0], 1);
    atomicAdd(&s_hist[i1], 1);
    __syncthreads();
    if (tid < NE) atomicAdd(&hist[tid], s_hist[tid]);
}

// ---------------- tiny exclusive scan ----------------
__global__ void k_scan(const int* __restrict__ hist, int* __restrict__ offs, int* __restrict__ cur)
{
    if (blockIdx.x == 0 && threadIdx.x == 0) {
        int acc = 0;
        for (int e = 0; e < NE; ++e) { offs[e] = acc; cur[e] = acc; acc += hist[e]; }
    }
}

// ---------------- block-aggregated scatter ----------------
__global__ __launch_bounds__(256) void k_scatter(
    const int* __restrict__ top_e, const float* __restrict__ top_w,
    int* __restrict__ cur, int* __restrict__ pair_b, float* __restrict__ pair_w)
{
    __shared__ int lh[NE];
    __shared__ int lbase[NE];
    const int tid = threadIdx.x;
    if (tid < NE) lh[tid] = 0;
    __syncthreads();

    const int b = blockIdx.x * 256 + tid;
    const int e0 = top_e[2*b+0];
    const int e1 = top_e[2*b+1];
    atomicAdd(&lh[e0], 1);
    atomicAdd(&lh[e1], 1);
    __syncthreads();
    if (tid < NE) {
        lbase[tid] = atomicAdd(&cur[tid], lh[tid]);
        lh[tid] = 0;
    }
    __syncthreads();
    int r0 = atomicAdd(&lh[e0], 1);
    int p0 = lbase[e0] + r0;
    pair_b[p0] = b; pair_w[p0] = top_w[2*b+0];
    int r1 = atomicAdd(&lh[e1], 1);
    int p1 = lbase[e1] + r1;
    pair_b[p1] = b; pair_w[p1] = top_w[2*b+1];
}

// ---------------- expert: fc1 (LDS row -> named z), LN, fc2 (static), atomic out ----------------
#define EXP_BX 256
__global__ __launch_bounds__(128) void k_expert(
    const float* __restrict__ h,
    const int* __restrict__ pair_b, const float* __restrict__ pair_w,
    const int* __restrict__ hist, const int* __restrict__ offs,
    const float* __restrict__ ew1, const float* __restrict__ eb1,
    const float* __restrict__ eg, const float* __restrict__ ebeta,
    const float* __restrict__ ew2, const float* __restrict__ eb2,
    float* __restrict__ out)
{
    const int e = blockIdx.y;
    const int cnt = hist[e];
    if ((int)(blockIdx.x * 128) >= cnt) return;

    __shared__ __align__(16) float4 s_w1[EMB * 16];    // 16 KB [d][j4]
    __shared__ __align__(16) float4 s_w2[EMB * 3];     // 3 KB  [k][c4], 10->12 padded
    __shared__ __align__(16) float4 s_b1[16], s_ga[16], s_be[16], s_b2[3];
    __shared__ float s_hb[128 * HSTRIDE];              // 33.3 KB

    const int tid = threadIdx.x;
    {
        const float4* g1 = (const float4*)(ew1 + (size_t)e * EMB * EMB);
        for (int i = tid; i < EMB * 16; i += 128) s_w1[i] = g1[i];
        float* w2f = (float*)s_w2;
        for (int i = tid; i < EMB * 12; i += 128) {
            int k = i / 12, c = i - k * 12;
            w2f[i] = (c < NCLS) ? ew2[((size_t)e * EMB + k) * NCLS + c] : 0.0f;
        }
        if (tid < 16) {
            s_b1[tid] = ((const float4*)(eb1   + (size_t)e * EMB))[tid];
            s_ga[tid] = ((const float4*)(eg    + (size_t)e * EMB))[tid];
            s_be[tid] = ((const float4*)(ebeta + (size_t)e * EMB))[tid];
        }
        float* b2f = (float*)s_b2;
        if (tid < 12) b2f[tid] = (tid < NCLS) ? eb2[e * NCLS + tid] : 0.0f;
    }
    __syncthreads();

    const int base = offs[e];
    const int hbase = tid * HSTRIDE;

    for (int l0 = blockIdx.x * 128; l0 < cnt; l0 += EXP_BX * 128) {
        const int lane = l0 + tid;
        if (lane >= cnt) continue;
        const int idx = base + lane;
        const int b = pair_b[idx];
        const float pw = pair_w[idx];

        // stage own h row into LDS (runtime-indexable, conflict-free stride)
        const float4* hp = (const float4*)(h + (size_t)b * EMB);
#pragma unroll
        for (int t = 0; t < 16; ++t) {
            float4 hv4 = hp[t];
            float* hw = &s_hb[hbase + 4 * t];
            hw[0] = hv4.x; hw[1] = hv4.y; hw[2] = hv4.z; hw[3] = hv4.w;
        }

        // fc1 -> named z0..zf (4 static chunks)
        float4 z0, z1, z2, z3, z4, z5, z6, z7, z8, z9, za, zb, zc, zd, ze, zf;
#define EX_FC1C(KC, Z0, Z1, Z2, Z3) do { \
    float4 a0 = s_b1[(KC)*4+0], a1 = s_b1[(KC)*4+1], a2 = s_b1[(KC)*4+2], a3 = s_b1[(KC)*4+3]; \
    const float4* wr = s_w1 + (KC) * 4; \
    _Pragma("unroll 2") \
    for (int t = 0; t < 16; ++t) { \
        const float* hr = &s_hb[hbase + 4 * t]; \
        float q0 = hr[0], q1 = hr[1], q2 = hr[2], q3 = hr[3]; \
        a0 = sfma4(q0, wr[0], a0); a1 = sfma4(q0, wr[1], a1); a2 = sfma4(q0, wr[2], a2); a3 = sfma4(q0, wr[3], a3); wr += 16; \
        a0 = sfma4(q1, wr[0], a0); a1 = sfma4(q1, wr[1], a1); a2 = sfma4(q1, wr[2], a2); a3 = sfma4(q1, wr[3], a3); wr += 16; \
        a0 = sfma4(q2, wr[0], a0); a1 = sfma4(q2, wr[1], a1); a2 = sfma4(q2, wr[2], a2); a3 = sfma4(q2, wr[3], a3); wr += 16; \
        a0 = sfma4(q3, wr[0], a0); a1 = sfma4(q3, wr[1], a1); a2 = sfma4(q3, wr[2], a2); a3 = sfma4(q3, wr[3], a3); wr += 16; \
    } \
    Z0 = gelu4(a0); Z1 = gelu4(a1); Z2 = gelu4(a2); Z3 = gelu4(a3); \
} while (0)
        EX_FC1C(0, z0, z1, z2, z3);
        EX_FC1C(1, z4, z5, z6, z7);
        EX_FC1C(2, z8, z9, za, zb);
        EX_FC1C(3, zc, zd, ze, zf);
#undef EX_FC1C

        // LayerNorm (static over named regs)
        float4 sA = add4(add4(add4(z0, z1), add4(z2, z3)), add4(add4(z4, z5), add4(z6, z7)));
        float4 sB = add4(add4(add4(z8, z9), add4(za, zb)), add4(add4(zc, zd), add4(ze, zf)));
        float4 sS = add4(sA, sB);
        float mu = (sS.x + sS.y + sS.z + sS.w) * (1.0f / 64.0f);
        float4 vv = make_float4(0.f, 0.f, 0.f, 0.f);
#define EX_VACC(Z) do { float4 d4; d4.x = (Z).x - mu; d4.y = (Z).y - mu; d4.z = (Z).z - mu; d4.w = (Z).w - mu; \
                        vv = ffma4(d4, d4, vv); } while (0)
        EX_VACC(z0); EX_VACC(z1); EX_VACC(z2); EX_VACC(z3);
        EX_VACC(z4); EX_VACC(z5); EX_VACC(z6); EX_VACC(z7);
        EX_VACC(z8); EX_VACC(z9); EX_VACC(za); EX_VACC(zb);
        EX_VACC(zc); EX_VACC(zd); EX_VACC(ze); EX_VACC(zf);
#undef EX_VACC
        float var = (vv.x + vv.y + vv.z + vv.w) * (1.0f / 64.0f);
        float inv = 1.0f / sqrtf(var + 1e-5f);
        z0 = ln4(z0, mu, inv, s_ga[0],  s_be[0]);
        z1 = ln4(z1, mu, inv, s_ga[1],  s_be[1]);
        z2 = ln4(z2, mu, inv, s_ga[2],  s_be[2]);
        z3 = ln4(z3, mu, inv, s_ga[3],  s_be[3]);
        z4 = ln4(z4, mu, inv, s_ga[4],  s_be[4]);
        z5 = ln4(z5, mu, inv, s_ga[5],  s_be[5]);
        z6 = ln4(z6, mu, inv, s_ga[6],  s_be[6]);
        z7 = ln4(z7, mu, inv, s_ga[7],  s_be[7]);
        z8 = ln4(z8, mu, inv, s_ga[8],  s_be[8]);
        z9 = ln4(z9, mu, inv, s_ga[9],  s_be[9]);
        za = ln4(za, mu, inv, s_ga[10], s_be[10]);
        zb = ln4(zb, mu, inv, s_ga[11], s_be[11]);
        zc = ln4(zc, mu, inv, s_ga[12], s_be[12]);
        zd = ln4(zd, mu, inv, s_ga[13], s_be[13]);
        ze = ln4(ze, mu, inv, s_ga[14], s_be[14]);
        zf = ln4(zf, mu, inv, s_ga[15], s_be[15]);

        // fc2 (64 -> 12 padded), fully static over named z
        float4 a0 = s_b2[0], a1 = s_b2[1], a2 = s_b2[2];
#define EX_FC2ST(ZQ, DB) do { \
        const float4* wr = s_w2 + (DB) * 3; \
        a0 = sfma4((ZQ).x, wr[0],  a0); a1 = sfma4((ZQ).x, wr[1],  a1); a2 = sfma4((ZQ).x, wr[2],  a2); \
        a0 = sfma4((ZQ).y, wr[3],  a0); a1 = sfma4((ZQ).y, wr[4],  a1); a2 = sfma4((ZQ).y, wr[5],  a2); \
        a0 = sfma4((ZQ).z, wr[6],  a0); a1 = sfma4((ZQ).z, wr[7],  a1); a2 = sfma4((ZQ).z, wr[8],  a2); \
        a0 = sfma4((ZQ).w, wr[9],  a0); a1 = sfma4((ZQ).w, wr[10], a1); a2 = sfma4((ZQ).w, wr[11], a2); \
} while (0)
        EX_FC2ST(z0, 0);  EX_FC2ST(z1, 4);  EX_FC2ST(z2, 8);  EX_FC2ST(z3, 12);
        EX_FC2ST(z4, 16); EX_FC2ST(z5, 20); EX_FC2ST(z6, 24); EX_FC2ST(z7, 28);
        EX_FC2ST(z8, 32); EX_FC2ST(z9, 36); EX_FC2ST(za, 40); EX_FC2ST(zb, 44);
        EX_FC2ST(zc, 48); EX_FC2ST(zd, 52); EX_FC2ST(ze, 56); EX_FC2ST(zf, 60);
#undef EX_FC2ST

        float* ob = out + (size_t)b * NCLS;
        atomicAdd(ob + 0, pw * a0.x);
        atomicAdd(ob + 1, pw * a0.y);
        atomicAdd(ob + 2, pw * a0.z);
        atomicAdd(ob + 3, pw * a0.w);
        atomicAdd(ob + 4, pw * a1.x);
        atomicAdd(ob + 5, pw * a1.y);
        atomicAdd(ob + 6, pw * a1.z);
        atomicAdd(ob + 7, pw * a1.w);
        atomicAdd(ob + 8, pw * a2.x);
        atomicAdd(ob + 9, pw * a2.y);
    }
}

extern "C" void kernel_launch(void* const* d_in, const int* in_sizes, int n_in,
                              void* d_out, int out_size, void* d_ws, size_t ws_size,
                              hipStream_t stream)
{
    (void)in_sizes; (void)n_in; (void)out_size; (void)ws_size;

    const float* x     = (const float*)d_in[0];
    const int*   uid   = (const int*)  d_in[1];
    const float* bb_w1 = (const float*)d_in[2];
    const float* bb_b1 = (const float*)d_in[3];
    const float* bb_w2 = (const float*)d_in[4];
    const float* bb_b2 = (const float*)d_in[5];
    const float* bb_g  = (const float*)d_in[6];
    const float* bb_be = (const float*)d_in[7];
    const float* gU    = (const float*)d_in[8];
    const float* gV    = (const float*)d_in[9];
    const float* gb    = (const float*)d_in[10];
    const float* e_w1  = (const float*)d_in[11];
    const float* e_b1  = (const float*)d_in[12];
    const float* e_g   = (const float*)d_in[13];
    const float* e_be  = (const float*)d_in[14];
    const float* e_w2  = (const float*)d_in[15];
    const float* e_b2  = (const float*)d_in[16];
    const float* ut    = (const float*)d_in[17];

    float* out = (float*)d_out;
    char*  ws  = (char*)d_ws;

    float* h      = (float*)(ws + OFF_H);
    float* A      = (float*)(ws + OFF_A);
    int*   top_e  = (int*)  (ws + OFF_TOPE);
    float* top_w  = (float*)(ws + OFF_TOPW);
    int*   pair_b = (int*)  (ws + OFF_PAIRB);
    float* pair_w = (float*)(ws + OFF_PAIRW);
    int*   hist   = (int*)  (ws + OFF_HIST);
    int*   offs   = (int*)  (ws + OFF_OFFS);
    int*   cur    = (int*)  (ws + OFF_CUR);

    hipMemsetAsync(out, 0, (size_t)BATCH * NCLS * sizeof(float), stream);
    hipMemsetAsync(hist, 0, NE * sizeof(int), stream);

    k_prep<<<(NUSERS * NE + 255) / 256, 256, 0, stream>>>(gU, gV, ut, A);
    k_backbone<<<BATCH / 128, 128, 0, stream>>>(x, bb_w1, bb_b1, bb_w2, bb_b2,
                                                bb_g, bb_be, h);
    k_gate2<<<BATCH / 256, 256, 0, stream>>>(h, uid, A, gb, top_e, top_w, hist);
    k_scan<<<1, 64, 0, stream>>>(hist, offs, cur);
    k_scatter<<<BATCH / 256, 256, 0, stream>>>(top_e, top_w, cur, pair_b, pair_w);
    dim3 eg(EXP_BX, NE);
    k_expert<<<eg, 128, 0, stream>>>(h, pair_b, pair_w, hist, offs,
                                     e_w1, e_b1, e_g, e_be, e_w2, e_b2, out);
}